// Round 5
// baseline (412.614 us; speedup 1.0000x reference)
//
#include <hip/hip_runtime.h>
#include <stdint.h>

#define T_LEN 2048
#define B_TOT 64
#define N_TAG 128
#define MID 1024  // fwd applies M_1..M_{MID-1}; bwd applies M'_{MID}..M'_{T-1}

typedef __attribute__((ext_vector_type(4))) float f32x4;
typedef __attribute__((ext_vector_type(8))) short bf16x8;
typedef __attribute__((ext_vector_type(4))) uint32_t u32x4;
typedef __attribute__((ext_vector_type(2))) uint32_t u32x2;

template <int S>
struct IC {
  static constexpr int value = S;
};

// mid-boundary handoff (written by scan blocks, combined by the last block
// to finish via device-scope ticket; __threadfence gives cross-XCD visibility)
__device__ __align__(16) float g_alpha[B_TOT][N_TAG];
__device__ __align__(16) float g_v[B_TOT][N_TAG];
__device__ float g_Lf[B_TOT];
__device__ float g_Lb[B_TOT];
__device__ int g_done = 0;

// pack two fp32 -> dword of two bf16 (round-half-up); elem0 in low half
__device__ __forceinline__ uint32_t pack2_bf16(float a, float b) {
  uint32_t ua = __float_as_uint(a) + 0x8000u;
  uint32_t ub = __float_as_uint(b) + 0x8000u;
  return __builtin_amdgcn_perm(ua, ub, 0x03020706u);
}
__device__ __forceinline__ float bf_lo(uint32_t w) {
  return __uint_as_float(w << 16);
}
__device__ __forceinline__ float bf_hi(uint32_t w) {
  return __uint_as_float(w & 0xffff0000u);
}

// prepass: ws[t][b][i] = bf16(exp(em[b][t][i])), i-pairs packed in u32.
// Separate launch (R4 showed fusing this traffic into the scan poisons the
// latency-critical loop); stream order guarantees visibility to the scan.
__global__ __launch_bounds__(256) void eem_prepass(const float* __restrict__ em,
                                                   uint32_t* __restrict__ ws) {
  const int tid = blockIdx.x * blockDim.x + threadIdx.x;  // 0 .. 2^21-1
  const int b = tid >> 15;
  const int rem = tid & 32767;
  const int t = rem >> 4;
  const int kk = rem & 15;  // 8 floats per thread
  const float4* src =
      (const float4*)(em + ((size_t)b * T_LEN + t) * N_TAG + kk * 8);
  const float4 p0 = src[0];
  const float4 p1 = src[1];
  u32x4 o;
  o[0] = pack2_bf16(__expf(p0.x), __expf(p0.y));
  o[1] = pack2_bf16(__expf(p0.z), __expf(p0.w));
  o[2] = pack2_bf16(__expf(p1.x), __expf(p1.y));
  o[3] = pack2_bf16(__expf(p1.z), __expf(p1.w));
  *(u32x4*)(ws + ((size_t)t * B_TOT + b) * (N_TAG / 2) + kk * 4) = o;
}

// Two-ended scan, 4-wave structure (R5 redesign):
//   blocks 0-3 fwd (t=1..1023, maskless: len>=1024), blocks 4-7 bwd
//   (t=2047..1024, per-lane identity select for t>=len).
// Wave w (0..3) owns the FULL fragment w (32 j's = 2 MFMA m-tiles, 8 MFMAs
// as 4 independent 2-chains). vs the 8-wave version this HALVES the LDS
// broadcast-read traffic (16KB vs 32KB per step) -- the dominant step cost --
// and turns the state write into one conflict-free ds_write_b128.
// A rows permuted per tile: tile mt row m=q*4+r -> j = 32w + 8q + 4mt + r,
// so the two f32x4 D outputs concatenate into exactly this lane's 8-value
// B-fragment slot: zero cross-lane traffic, 4 ds_read_b128 + 1 ds_write_b128
// per wave per step. 8-slot eem prefetch ring (u32x4/lane).
__global__ __launch_bounds__(256, 1) void crf_scan_kernel(
    const float* __restrict__ em, const int* __restrict__ lens,
    const float* __restrict__ trans, const float* __restrict__ head,
    const float* __restrict__ last, const uint32_t* __restrict__ eem,
    float* __restrict__ out) {
  const int lane = threadIdx.x & 63;
  const int w = threadIdx.x >> 6;  // 0..3, owns fragment w
  const int c = lane & 15;         // batch-in-tile
  const int q = lane >> 4;         // 0..3
  const bool is_fwd = (blockIdx.x < 4);
  const int bg = ((int)blockIdx.x & 3) * 16 + c;
  const int jb = w * 32 + q * 8;  // lane's 8 state indices jb..jb+7

  __shared__ uint32_t x_lds[2][4][64][4];  // [pingpong][frag][lane][dword]
  __shared__ int k_lds[16];
  __shared__ int ticket_lds;

  // per-lane emission pointer: 8 bf16 (u32x4) of row for this lane's 8 j's
  const uint32_t* eqp = eem + (size_t)bg * 64 + w * 16 + q * 4;
  u32x4 eslot[8];
  auto issue_eem = [&](auto sc, int row) {
    constexpr int S = decltype(sc)::value;
    eslot[S] = *(const u32x4*)(eqp + (size_t)row * 4096);
  };

  const f32x4 vzero = {0.f, 0.f, 0.f, 0.f};

  if (is_fwd) {
    // ================= forward half: produce alpha_{MID-1} =================
    // A[mt][kt]: m-tile mt of fragment w; A[m][k=i] = exp(trans[i][j(m)]),
    // j(m) = 32w + (m>>2)*8 + 4*mt + (m&3)
    bf16x8 efrag[2][4];
#pragma unroll
    for (int mt = 0; mt < 2; ++mt) {
      const int j = w * 32 + (c >> 2) * 8 + mt * 4 + (c & 3);
#pragma unroll
      for (int ktp = 0; ktp < 4; ++ktp) {
        u32x4 wd;
#pragma unroll
        for (int p = 0; p < 4; ++p) {
          const int i0 = ktp * 32 + q * 8 + 2 * p;
          wd[p] = pack2_bf16(__expf(trans[(i0 + 0) * N_TAG + j]),
                             __expf(trans[(i0 + 1) * N_TAG + j]));
        }
        efrag[mt][ktp] = __builtin_bit_cast(bf16x8, wd);
      }
    }
    float L = 0.f;
    {
      const float* emb = em + (size_t)bg * T_LEN * N_TAG;
      float v0[8];
#pragma unroll
      for (int r = 0; r < 8; ++r) v0[r] = __expf(head[jb + r] + emb[jb + r]);
      u32x4 wd;
#pragma unroll
      for (int d = 0; d < 4; ++d) wd[d] = pack2_bf16(v0[2 * d], v0[2 * d + 1]);
      *(u32x4*)&x_lds[0][w][lane][0] = wd;
    }
    if (w == 0 && lane < 16) k_lds[lane] = 0;
    __syncthreads();

    issue_eem(IC<1>{}, 1);
    issue_eem(IC<2>{}, 2);
    issue_eem(IC<3>{}, 3);
    issue_eem(IC<4>{}, 4);
    issue_eem(IC<5>{}, 5);
    issue_eem(IC<6>{}, 6);
    issue_eem(IC<7>{}, 7);

    auto step = [&](auto slotc, int t) {
      constexpr int SLOT = decltype(slotc)::value;
      constexpr int RP = (SLOT + 1) & 1;
      constexpr int WP = SLOT & 1;
      {
        int row = t + 7;
        if (row > T_LEN - 1) row = T_LEN - 1;
        issue_eem(IC<(SLOT + 7) & 7>{}, row);  // refill freed slot
      }
      int e = 0;
      if ((SLOT & 3) == 1) e = k_lds[c];
      u32x4 bfr[4];
#pragma unroll
      for (int ktv = 0; ktv < 4; ++ktv)
        bfr[ktv] = *(const u32x4*)&x_lds[RP][(w + ktv) & 3][lane][0];
      const u32x4 ev = eslot[SLOT];
      float ff[8];
#pragma unroll
      for (int d = 0; d < 4; ++d) {
        ff[2 * d] = bf_lo(ev[d]);
        ff[2 * d + 1] = bf_hi(ev[d]);
      }
      if ((SLOT & 3) == 1) {
        const float sc = __uint_as_float((uint32_t)(127 - e) << 23);
#pragma unroll
        for (int r = 0; r < 8; ++r) ff[r] *= sc;
        L += (float)e * 0.6931471805599453f;
      }
      // 2 output tiles x 2 parallel 2-deep chains = 4 independent chains
      f32x4 x0 = __builtin_amdgcn_mfma_f32_16x16x32_bf16(
          efrag[0][(w + 0) & 3], __builtin_bit_cast(bf16x8, bfr[0]), vzero, 0,
          0, 0);
      f32x4 y0 = __builtin_amdgcn_mfma_f32_16x16x32_bf16(
          efrag[0][(w + 2) & 3], __builtin_bit_cast(bf16x8, bfr[2]), vzero, 0,
          0, 0);
      f32x4 x1 = __builtin_amdgcn_mfma_f32_16x16x32_bf16(
          efrag[1][(w + 0) & 3], __builtin_bit_cast(bf16x8, bfr[0]), vzero, 0,
          0, 0);
      f32x4 y1 = __builtin_amdgcn_mfma_f32_16x16x32_bf16(
          efrag[1][(w + 2) & 3], __builtin_bit_cast(bf16x8, bfr[2]), vzero, 0,
          0, 0);
      x0 = __builtin_amdgcn_mfma_f32_16x16x32_bf16(
          efrag[0][(w + 1) & 3], __builtin_bit_cast(bf16x8, bfr[1]), x0, 0, 0,
          0);
      y0 = __builtin_amdgcn_mfma_f32_16x16x32_bf16(
          efrag[0][(w + 3) & 3], __builtin_bit_cast(bf16x8, bfr[3]), y0, 0, 0,
          0);
      x1 = __builtin_amdgcn_mfma_f32_16x16x32_bf16(
          efrag[1][(w + 1) & 3], __builtin_bit_cast(bf16x8, bfr[1]), x1, 0, 0,
          0);
      y1 = __builtin_amdgcn_mfma_f32_16x16x32_bf16(
          efrag[1][(w + 3) & 3], __builtin_bit_cast(bf16x8, bfr[3]), y1, 0, 0,
          0);
      const f32x4 a0 = x0 + y0;  // j = jb + 0..3
      const f32x4 a1 = x1 + y1;  // j = jb + 4..7
      if ((SLOT & 3) == 0) {
        // exponent probe of j=0: wave 0 lanes 0-15 hold alpha[0][c] in a0[0]
        if (w == 0 && lane < 16)
          k_lds[c] = (int)(__float_as_uint(a0[0]) >> 23) - 126;
      }
      if (t == MID - 1) {  // mid-boundary capture (f32 precision)
#pragma unroll
        for (int r = 0; r < 4; ++r) {
          g_alpha[bg][jb + r] = a0[r] * ff[r];
          g_alpha[bg][jb + 4 + r] = a1[r] * ff[4 + r];
        }
        if (w == 0 && lane < 16) g_Lf[bg] = L;
      }
      u32x4 wd;
      wd[0] = pack2_bf16(a0[0] * ff[0], a0[1] * ff[1]);
      wd[1] = pack2_bf16(a0[2] * ff[2], a0[3] * ff[3]);
      wd[2] = pack2_bf16(a1[0] * ff[4], a1[1] * ff[5]);
      wd[3] = pack2_bf16(a1[2] * ff[6], a1[3] * ff[7]);
      *(u32x4*)&x_lds[WP][w][lane][0] = wd;  // conflict-free b128
      __syncthreads();
    };

    int t = 1;
#pragma unroll 1
    for (int it = 0; it < 127; ++it) {  // t = 1 .. 1016
      step(IC<1>{}, t);
      step(IC<2>{}, t + 1);
      step(IC<3>{}, t + 2);
      step(IC<4>{}, t + 3);
      step(IC<5>{}, t + 4);
      step(IC<6>{}, t + 5);
      step(IC<7>{}, t + 6);
      step(IC<0>{}, t + 7);
      t += 8;
    }
    step(IC<1>{}, t);      // 1017
    step(IC<2>{}, t + 1);  // 1018
    step(IC<3>{}, t + 2);  // 1019
    step(IC<4>{}, t + 3);  // 1020
    step(IC<5>{}, t + 4);  // 1021
    step(IC<6>{}, t + 5);  // 1022
    step(IC<7>{}, t + 6);  // 1023 (capture)
  } else {
    // ================= backward half: produce v_MID =================
    // A[mt][kt]: A[m][k=j'] = exp(trans[i(m)][j']),
    // i(m) = 32w + (m>>2)*8 + 4*mt + (m&3)
    bf16x8 efrag[2][4];
#pragma unroll
    for (int mt = 0; mt < 2; ++mt) {
      const int irow = w * 32 + (c >> 2) * 8 + mt * 4 + (c & 3);
#pragma unroll
      for (int ktp = 0; ktp < 4; ++ktp) {
        u32x4 wd;
#pragma unroll
        for (int p = 0; p < 4; ++p) {
          const int j0 = ktp * 32 + q * 8 + 2 * p;
          wd[p] = pack2_bf16(__expf(trans[irow * N_TAG + j0 + 0]),
                             __expf(trans[irow * N_TAG + j0 + 1]));
        }
        efrag[mt][ktp] = __builtin_bit_cast(bf16x8, wd);
      }
    }
    const int mylen = lens[bg];
    float L = 0.f;
    float vprev[8];
    {
      // v_T = exp(last); LDS gets u_{T-1} = e_{T-1} (*) v_T
#pragma unroll
      for (int r = 0; r < 8; ++r) vprev[r] = __expf(last[jb + r]);
      const u32x4 e0 = *(const u32x4*)(eqp + (size_t)(T_LEN - 1) * 4096);
      u32x4 wd;
#pragma unroll
      for (int d = 0; d < 4; ++d)
        wd[d] = pack2_bf16(vprev[2 * d] * bf_lo(e0[d]),
                           vprev[2 * d + 1] * bf_hi(e0[d]));
      *(u32x4*)&x_lds[0][w][lane][0] = wd;
    }
    if (w == 0 && lane < 16) k_lds[lane] = 0;
    __syncthreads();

    // slot k holds row 2047-k (consumed as e_{t-1} at step t = 2048-k)
    issue_eem(IC<1>{}, T_LEN - 2);
    issue_eem(IC<2>{}, T_LEN - 3);
    issue_eem(IC<3>{}, T_LEN - 4);
    issue_eem(IC<4>{}, T_LEN - 5);
    issue_eem(IC<5>{}, T_LEN - 6);
    issue_eem(IC<6>{}, T_LEN - 7);
    issue_eem(IC<7>{}, T_LEN - 8);

    auto step = [&](auto slotc, int t) {
      constexpr int SLOT = decltype(slotc)::value;
      constexpr int RP = (SLOT + 1) & 1;
      constexpr int WP = SLOT & 1;
      issue_eem(IC<(SLOT + 7) & 7>{}, t - 8);  // refill (min row 1016)
      int e = 0;
      if ((SLOT & 3) == 1) e = k_lds[c];
      u32x4 bfr[4];
#pragma unroll
      for (int ktv = 0; ktv < 4; ++ktv)
        bfr[ktv] = *(const u32x4*)&x_lds[RP][(w + ktv) & 3][lane][0];
      const u32x4 ev = eslot[SLOT];  // e_{t-1}, for packing u_{t-1}
      float ee[8];
#pragma unroll
      for (int d = 0; d < 4; ++d) {
        ee[2 * d] = bf_lo(ev[d]);
        ee[2 * d + 1] = bf_hi(ev[d]);
      }
      f32x4 x0 = __builtin_amdgcn_mfma_f32_16x16x32_bf16(
          efrag[0][(w + 0) & 3], __builtin_bit_cast(bf16x8, bfr[0]), vzero, 0,
          0, 0);
      f32x4 y0 = __builtin_amdgcn_mfma_f32_16x16x32_bf16(
          efrag[0][(w + 2) & 3], __builtin_bit_cast(bf16x8, bfr[2]), vzero, 0,
          0, 0);
      f32x4 x1 = __builtin_amdgcn_mfma_f32_16x16x32_bf16(
          efrag[1][(w + 0) & 3], __builtin_bit_cast(bf16x8, bfr[0]), vzero, 0,
          0, 0);
      f32x4 y1 = __builtin_amdgcn_mfma_f32_16x16x32_bf16(
          efrag[1][(w + 2) & 3], __builtin_bit_cast(bf16x8, bfr[2]), vzero, 0,
          0, 0);
      x0 = __builtin_amdgcn_mfma_f32_16x16x32_bf16(
          efrag[0][(w + 1) & 3], __builtin_bit_cast(bf16x8, bfr[1]), x0, 0, 0,
          0);
      y0 = __builtin_amdgcn_mfma_f32_16x16x32_bf16(
          efrag[0][(w + 3) & 3], __builtin_bit_cast(bf16x8, bfr[3]), y0, 0, 0,
          0);
      x1 = __builtin_amdgcn_mfma_f32_16x16x32_bf16(
          efrag[1][(w + 1) & 3], __builtin_bit_cast(bf16x8, bfr[1]), x1, 0, 0,
          0);
      y1 = __builtin_amdgcn_mfma_f32_16x16x32_bf16(
          efrag[1][(w + 3) & 3], __builtin_bit_cast(bf16x8, bfr[3]), y1, 0, 0,
          0);
      const f32x4 a0 = x0 + y0;  // i = jb + 0..3
      const f32x4 a1 = x1 + y1;  // i = jb + 4..7
      // identity select for padded steps (t >= len): keep v unchanged
      const bool valid = (t < mylen);
      float vnew[8];
#pragma unroll
      for (int r = 0; r < 4; ++r) {
        vnew[r] = valid ? a0[r] : vprev[r];
        vnew[4 + r] = valid ? a1[r] : vprev[4 + r];
      }
      if ((SLOT & 3) == 1) {
        const float sc = __uint_as_float((uint32_t)(127 - e) << 23);
#pragma unroll
        for (int r = 0; r < 8; ++r) vnew[r] *= sc;
        L += (float)e * 0.6931471805599453f;
      }
      if ((SLOT & 3) == 0) {
        if (w == 0 && lane < 16)
          k_lds[c] = (int)(__float_as_uint(vnew[0]) >> 23) - 126;
      }
      if (t == MID) {  // mid-boundary capture
#pragma unroll
        for (int r = 0; r < 8; ++r) g_v[bg][jb + r] = vnew[r];
        if (w == 0 && lane < 16) g_Lb[bg] = L;
      }
      u32x4 wd;
#pragma unroll
      for (int d = 0; d < 4; ++d)
        wd[d] = pack2_bf16(vnew[2 * d] * ee[2 * d],
                           vnew[2 * d + 1] * ee[2 * d + 1]);
      *(u32x4*)&x_lds[WP][w][lane][0] = wd;  // conflict-free b128
#pragma unroll
      for (int r = 0; r < 8; ++r) vprev[r] = vnew[r];
      __syncthreads();
    };

    int t = T_LEN - 1;  // 2047
#pragma unroll 1
    for (int it = 0; it < 128; ++it) {  // t = 2047 .. 1024 (capture at 1024)
      step(IC<1>{}, t);
      step(IC<2>{}, t - 1);
      step(IC<3>{}, t - 2);
      step(IC<4>{}, t - 3);
      step(IC<5>{}, t - 4);
      step(IC<6>{}, t - 5);
      step(IC<7>{}, t - 6);
      step(IC<0>{}, t - 7);
      t -= 8;
    }
  }

  // ===== last-block combine: Z[b] = log(sum_j alpha*v) + Lf + Lb =====
  __threadfence();  // publish this block's g_alpha / g_v / g_Lf / g_Lb
  if (threadIdx.x == 0) ticket_lds = atomicAdd(&g_done, 1);
  __syncthreads();
  if (ticket_lds == 7) {
    __threadfence();  // acquire: other blocks' captures
    const int b = threadIdx.x >> 2;  // 64 batches x 4 threads
    const int p = threadIdx.x & 3;
    float s = 0.f;
#pragma unroll
    for (int k = 0; k < 8; ++k) {
      const f32x4 a = *(const f32x4*)&g_alpha[b][p * 32 + k * 4];
      const f32x4 v = *(const f32x4*)&g_v[b][p * 32 + k * 4];
      s += a[0] * v[0] + a[1] * v[1] + a[2] * v[2] + a[3] * v[3];
    }
    s += __shfl_xor(s, 1);
    s += __shfl_xor(s, 2);
    if (p == 0) out[b] = __logf(s) + g_Lf[b] + g_Lb[b];
    __syncthreads();
    if (threadIdx.x == 0) g_done = 0;  // reset for next replay
  }
}

extern "C" void kernel_launch(void* const* d_in, const int* in_sizes, int n_in,
                              void* d_out, int out_size, void* d_ws,
                              size_t ws_size, hipStream_t stream) {
  const float* em = (const float*)d_in[0];
  const int* lens = (const int*)d_in[1];
  const float* trans = (const float*)d_in[2];
  const float* head = (const float*)d_in[3];
  const float* last = (const float*)d_in[4];
  float* out = (float*)d_out;
  uint32_t* ws = (uint32_t*)d_ws;  // 2048*64*128 bf16 = 32 MiB

  eem_prepass<<<8192, 256, 0, stream>>>(em, ws);
  crf_scan_kernel<<<8, 256, 0, stream>>>(em, lens, trans, head, last, ws, out);
}